// Round 2
// baseline (62.546 us; speedup 1.0000x reference)
//
#include <hip/hip_runtime.h>

// CapsuleRoutingPooling collapses analytically:
//   softmax over singleton axis 3 == 1.0, so routing logits never matter.
//   out = squash(2x2 sum-pool of D=16 vectors).
// Shapes: B=16, C=64, H=64, W=64, D=16, k=2 -> out (16,64,32,32,16) f32.
//
// Memory-bound: 268 MB read + 67 MB write, every byte touched once.
// R2: grid-stride (2048 blocks) + nontemporal streaming loads/stores.

#define B_  16
#define C_  64
#define H_  64
#define W_  64
#define D_  16
#define NH_ 32
#define NW_ 32
#define NVEC (B_ * C_ * NH_ * NW_)   // 1,048,576 output vectors

typedef float f4 __attribute__((ext_vector_type(4)));

__global__ __launch_bounds__(256)
void caps_pool_squash_kernel(const float* __restrict__ in, float* __restrict__ out) {
    const unsigned stride = gridDim.x * 256u;
    const unsigned total  = NVEC * 4u;   // 4 threads per output vector

    for (unsigned tid = blockIdx.x * 256u + threadIdx.x; tid < total; tid += stride) {
        const unsigned vec = tid >> 2;   // output vector index
        const unsigned q   = tid & 3u;   // which float4 of the D=16 vector

        const unsigned bc  = vec >> 10;        // NH*NW = 1024
        const unsigned rem = vec & 1023u;
        const unsigned nh  = rem >> 5;         // NW = 32
        const unsigned nw  = rem & 31u;

        // input element index of (bc, h=2*nh, w=2*nw, d=4*q)
        const unsigned base = ((bc * H_ + 2u * nh) * W_ + 2u * nw) * D_ + q * 4u;

        const f4 a = __builtin_nontemporal_load((const f4*)(in + base));                // (h,   w)
        const f4 b = __builtin_nontemporal_load((const f4*)(in + base + D_));           // (h,   w+1)
        const f4 c = __builtin_nontemporal_load((const f4*)(in + base + W_ * D_));      // (h+1, w)
        const f4 d = __builtin_nontemporal_load((const f4*)(in + base + W_ * D_ + D_)); // (h+1, w+1)

        const f4 s = (a + b) + (c + d);

        // squared norm over D=16: per-lane partial, butterfly over the quad
        float p = s.x * s.x + s.y * s.y + s.z * s.z + s.w * s.w;
        p += __shfl_xor(p, 1, 64);
        p += __shfl_xor(p, 2, 64);

        // squash scale: sq/(1+sq) * 1/(sqrt(sq)+1e-8)
        const float scale = p / ((1.0f + p) * (sqrtf(p) + 1e-8f));

        const f4 v = s * scale;
        __builtin_nontemporal_store(v, (f4*)(out + vec * (unsigned)D_ + q * 4u));
    }
}

extern "C" void kernel_launch(void* const* d_in, const int* in_sizes, int n_in,
                              void* d_out, int out_size, void* d_ws, size_t ws_size,
                              hipStream_t stream) {
    const float* inp = (const float*)d_in[0];
    float* out = (float*)d_out;

    caps_pool_squash_kernel<<<2048, 256, 0, stream>>>(inp, out);
}

// Round 3
// 61.209 us; speedup vs baseline: 1.0218x; 1.0218x over previous
//
#include <hip/hip_runtime.h>

// CapsuleRoutingPooling collapses analytically:
//   softmax over singleton axis 3 == 1.0, so routing logits never matter.
//   out = squash(2x2 sum-pool of D=16 vectors).
// Shapes: B=16, C=64, H=64, W=64, D=16, k=2 -> out (16,64,32,32,16) f32.
//
// R3: fully dense per-instruction loads. A wave owns 16 consecutive output
// vectors (1 KB out); its input = 2 rows x 2 KB contiguous, loaded as 4
// dense 1 KB wave-loads. 2x2 pool + store-order repack done via shuffles.

#define B_  16
#define C_  64
#define H_  64
#define W_  64
#define D_  16
#define NVEC (B_ * C_ * 32 * 32)   // 1,048,576 output vectors

typedef float f4 __attribute__((ext_vector_type(4)));

__global__ __launch_bounds__(256)
void caps_pool_squash_kernel(const float* __restrict__ in, float* __restrict__ out) {
    const unsigned tid  = blockIdx.x * 256u + threadIdx.x;
    const unsigned wave = tid >> 6;    // 65,536 waves; wave owns 16 output vectors
    const unsigned lane = tid & 63u;

    // first output vector of this wave: ovec0 = wave*16
    // ovec = ((bc*32 + nh)*32 + nw); wave*16 -> nw0 in {0,16}
    const unsigned bc  = wave >> 6;            // ovec0 >> 10
    const unsigned rem = (wave << 4) & 1023u;  // ovec0 & 1023
    const unsigned nh  = rem >> 5;
    const unsigned nw0 = rem & 31u;            // 0 or 16

    // input float index of (bc, h=2*nh, w=2*nw0, d=0)
    const unsigned ibase = bc * (H_ * W_ * D_) + (2u * nh) * (W_ * D_) + (2u * nw0) * D_;

    // 4 dense 1 KB wave-loads: row h (2 KB) and row h+1 (2 KB)
    const f4 x0 = *(const f4*)(in + ibase + lane * 4u);                   // row h,   w-vecs 0..15
    const f4 x1 = *(const f4*)(in + ibase + 256u + lane * 4u);            // row h,   w-vecs 16..31
    const f4 y0 = *(const f4*)(in + ibase + 1024u + lane * 4u);           // row h+1, w-vecs 0..15
    const f4 y1 = *(const f4*)(in + ibase + 1280u + lane * 4u);           // row h+1, w-vecs 16..31

    // pool over h
    f4 z0 = x0 + y0;
    f4 z1 = x1 + y1;

    // pool over w: butterfly with the w-partner vector (4 lanes away).
    // afterwards lane l holds pooled sum for packed vec (l>>3), dup'd in l and l^4
    z0.x += __shfl_xor(z0.x, 4, 64);  z0.y += __shfl_xor(z0.y, 4, 64);
    z0.z += __shfl_xor(z0.z, 4, 64);  z0.w += __shfl_xor(z0.w, 4, 64);
    z1.x += __shfl_xor(z1.x, 4, 64);  z1.y += __shfl_xor(z1.y, 4, 64);
    z1.z += __shfl_xor(z1.z, 4, 64);  z1.w += __shfl_xor(z1.w, 4, 64);

    // repack to dense store order: dst lane l wants packed vec ov=l>>2, q=l&3.
    // ov<8 comes from z0 (src lane ov*8+q), ov>=8 from z1 (src (ov-8)*8+q).
    const int src = (int)(((lane >> 2) & 7u) * 8u + (lane & 3u));
    f4 s;
    {
        const float a0 = __shfl(z0.x, src, 64), b0 = __shfl(z1.x, src, 64);
        const float a1 = __shfl(z0.y, src, 64), b1 = __shfl(z1.y, src, 64);
        const float a2 = __shfl(z0.z, src, 64), b2 = __shfl(z1.z, src, 64);
        const float a3 = __shfl(z0.w, src, 64), b3 = __shfl(z1.w, src, 64);
        const bool lo = lane < 32u;
        s.x = lo ? a0 : b0;  s.y = lo ? a1 : b1;
        s.z = lo ? a2 : b2;  s.w = lo ? a3 : b3;
    }

    // squared norm over D=16 (quad of lanes), then squash scale
    float p = s.x * s.x + s.y * s.y + s.z * s.z + s.w * s.w;
    p += __shfl_xor(p, 1, 64);
    p += __shfl_xor(p, 2, 64);
    const float scale = p / ((1.0f + p) * (sqrtf(p) + 1e-8f));

    const f4 v = s * scale;

    // dense store: wave writes 1 KB contiguous
    *(f4*)(out + wave * 256u + lane * 4u) = v;
}

extern "C" void kernel_launch(void* const* d_in, const int* in_sizes, int n_in,
                              void* d_out, int out_size, void* d_ws, size_t ws_size,
                              hipStream_t stream) {
    const float* inp = (const float*)d_in[0];
    float* out = (float*)d_out;

    const unsigned waves  = NVEC / 16u;          // 65,536
    const unsigned blocks = (waves * 64u) / 256u; // 16,384
    caps_pool_squash_kernel<<<blocks, 256, 0, stream>>>(inp, out);
}